// Round 4
// baseline (1093.418 us; speedup 1.0000x reference)
//
#include <hip/hip_runtime.h>
#include <stdint.h>
#include <math.h>

#define T_SIM 500
#define NB    64
#define NIN   1024
#define NHID  1024
#define NOUT  10
#define KSRM  77     // SRM kernel taps 0..76 (srm[0] == 0)
#define CHUNK 32     // batches per chunk for layer-1 pipeline
#define TT    32     // t-tile inside fused psp+spike kernel
#define RING  140    // 76 history + 2*TT (double-buffer region)

// Reference builds kernels in python f64 then rounds to fp32; we reproduce the
// exact fp32 tap values and do all accumulation in f64 (verified: absmax 0).
__device__ __forceinline__ double srm_tap(int k) {
  double u = (double)k / 10.0;
  double v = u * exp(1.0 - u);
  return (double)(float)v;
}
__device__ __forceinline__ double ref_tap(int j) {
  double v = (-20.0 * (double)j) * exp(1.0 - (double)j);
  return (double)(float)v;
}

// ---------------------------------------------------------------------------
// K0: pack binary input spikes x[b][i][t] (fp32 0/1) -> bits [b][t][16 x u64]
__global__ __launch_bounds__(64)
void k_pack(const float* __restrict__ x, unsigned long long* __restrict__ bits) {
  const int b = blockIdx.x, ig = blockIdx.y, tc = blockIdx.z;
  const int lane = threadIdx.x;
  const float* xr = x + ((size_t)b * NIN + ig * 64 + lane) * T_SIM;
  const int t0 = tc * 100;
  for (int t = t0; t < t0 + 100; t += 4) {
    const float4 v = *(const float4*)(xr + t);
    unsigned long long m0 = __ballot(v.x > 0.5f);
    unsigned long long m1 = __ballot(v.y > 0.5f);
    unsigned long long m2 = __ballot(v.z > 0.5f);
    unsigned long long m3 = __ballot(v.w > 0.5f);
    if (lane == 0) {
      unsigned long long* w = bits + (size_t)(b * T_SIM + t) * 16 + ig;
      w[0] = m0; w[16] = m1; w[32] = m2; w[48] = m3;
    }
  }
}

// ---------------------------------------------------------------------------
// K0b: W1[o][i] -> W1T[i][o] fp32, tiled 64x64 through LDS.
__global__ __launch_bounds__(256)
void k_transpose(const float* __restrict__ W1, float* __restrict__ W1T) {
  __shared__ float tile[64][65];
  const int bo = blockIdx.x * 64, bi = blockIdx.y * 64;
  for (int k = threadIdx.x; k < 4096; k += 256) {
    int r = k >> 6, c = k & 63;
    tile[r][c] = W1[(size_t)(bo + r) * NIN + bi + c];
  }
  __syncthreads();
  for (int k = threadIdx.x; k < 4096; k += 256) {
    int r = k >> 6, c = k & 63;
    W1T[(size_t)(bi + r) * NHID + bo + c] = tile[c][r];
  }
}

// ---------------------------------------------------------------------------
// K1: dense1 sparse gather v2: decode active-index list once per column, then
// gather with 4 independent f64 accumulator sets (4 loads in flight).
// grid (CHUNK*500), block 256 (thread = 4 outputs). a1c [col_loc][1024] f64.
__global__ __launch_bounds__(256)
void k_dense1(const uint32_t* __restrict__ bits, const float* __restrict__ W1T,
              double* __restrict__ a1c, int col_base) {
  __shared__ int list[NIN];
  __shared__ int nact_s;
  const int col_loc = blockIdx.x;
  const int tid = threadIdx.x;
  // decode mask words (wave 0, lanes 0..31)
  if (tid < 32) {
    uint32_t w = bits[(size_t)(col_base + col_loc) * 32 + tid];
    int c = __popc(w);
    int p = c;
#pragma unroll
    for (int d = 1; d < 32; d <<= 1) {
      int q = __shfl_up(p, d);
      if (tid >= d) p += q;
    }
    int excl = p - c;
    while (w) {
      const int j = __ffs(w) - 1;
      w &= w - 1;
      list[excl++] = tid * 32 + j;   // i ascending overall
    }
    if (tid == 31) nact_s = excl;    // total count
  }
  __syncthreads();
  const int n = nact_s;
  const int o = tid * 4;
  double a0x=0,a0y=0,a0z=0,a0w=0, a1x=0,a1y=0,a1z=0,a1w=0;
  double a2x=0,a2y=0,a2z=0,a2w=0, a3x=0,a3y=0,a3z=0,a3w=0;
  int g = 0;
  for (; g + 4 <= n; g += 4) {
    const int i0 = list[g], i1 = list[g+1], i2 = list[g+2], i3 = list[g+3];
    const float4 w0 = *(const float4*)(W1T + (size_t)i0 * NHID + o);
    const float4 w1 = *(const float4*)(W1T + (size_t)i1 * NHID + o);
    const float4 w2 = *(const float4*)(W1T + (size_t)i2 * NHID + o);
    const float4 w3 = *(const float4*)(W1T + (size_t)i3 * NHID + o);
    a0x += (double)w0.x; a0y += (double)w0.y; a0z += (double)w0.z; a0w += (double)w0.w;
    a1x += (double)w1.x; a1y += (double)w1.y; a1z += (double)w1.z; a1w += (double)w1.w;
    a2x += (double)w2.x; a2y += (double)w2.y; a2z += (double)w2.z; a2w += (double)w2.w;
    a3x += (double)w3.x; a3y += (double)w3.y; a3z += (double)w3.z; a3w += (double)w3.w;
  }
  if (g + 0 < n) {
    const float4 wv = *(const float4*)(W1T + (size_t)list[g+0] * NHID + o);
    a0x += (double)wv.x; a0y += (double)wv.y; a0z += (double)wv.z; a0w += (double)wv.w;
  }
  if (g + 1 < n) {
    const float4 wv = *(const float4*)(W1T + (size_t)list[g+1] * NHID + o);
    a1x += (double)wv.x; a1y += (double)wv.y; a1z += (double)wv.z; a1w += (double)wv.w;
  }
  if (g + 2 < n) {
    const float4 wv = *(const float4*)(W1T + (size_t)list[g+2] * NHID + o);
    a2x += (double)wv.x; a2y += (double)wv.y; a2z += (double)wv.z; a2w += (double)wv.w;
  }
  double4 r;
  r.x = (a0x + a1x) + (a2x + a3x);
  r.y = (a0y + a1y) + (a2y + a3y);
  r.z = (a0z + a1z) + (a2z + a3z);
  r.w = (a0w + a1w) + (a2w + a3w);
  *(double4*)(a1c + (size_t)col_loc * NHID + o) = r;
}

// ---------------------------------------------------------------------------
// K2: FUSED psp1 + spike1 v2. 32 neurons/block; ring 140 rows with register
// prefetch pipeline (next tile loads overlap current FIR). Tap shift-register
// (1 LDS tap read/iter). Scan on lanes 0..31 -> u32 spike masks.
// grid (32, CHUNK), block 256. LDS: 140*32*8 + 32*32*8 + 80*8 = 44,672 B.
__global__ __launch_bounds__(256)
void k_ps1(const double* __restrict__ a1c, uint32_t* __restrict__ s1w,
           int b_base) {
  __shared__ double S[RING * 32];
  __shared__ double Y[TT * 32];
  __shared__ double srm[KSRM];
  const int ng = blockIdx.x, b_loc = blockIdx.y;
  const int tid = threadIdx.x;
  if (tid < KSRM) srm[tid] = srm_tap(tid);

  double refk[11];
#pragma unroll
  for (int j = 1; j <= 10; ++j) refk[j] = ref_tap(j);
  uint32_t smask = 0;

  const double* __restrict__ abase = a1c + (size_t)b_loc * T_SIM * NHID + ng * 32;
  uint32_t* __restrict__ sbase =
      s1w + (size_t)(b_base + b_loc) * T_SIM * 32 + ng;

  // ---- preamble: zero ring, prefetch+write tile 0 ----
  double pf[4];
  {
#pragma unroll
    for (int j = 0; j < 4; ++j) {
      const int id = tid + j * 256;          // id < 1024 always (tv0 = 32)
      const int r = id >> 5, n = id & 31;
      pf[j] = abase[(size_t)r * NHID + n];
    }
    for (int i = tid; i < RING * 32; i += 256) S[i] = 0.0;
    __syncthreads();
#pragma unroll
    for (int j = 0; j < 4; ++j) {
      const int id = tid + j * 256;
      const int r = id >> 5, n = id & 31;
      S[((r) % RING) * 32 + n] = pf[j];
    }
    __syncthreads();
  }

  for (int t0 = 0; t0 < T_SIM; t0 += TT) {
    const int tv = (T_SIM - t0 < TT) ? (T_SIM - t0) : TT;
    const int t0n = t0 + TT;
    const int tvn = (t0n >= T_SIM) ? 0 : ((T_SIM - t0n < TT) ? (T_SIM - t0n) : TT);
    // ---- prefetch next tile into registers (loads overlap FIR below) ----
#pragma unroll
    for (int j = 0; j < 4; ++j) {
      const int id = tid + j * 256;
      if (id < tvn * 32) {
        const int r = id >> 5, n = id & 31;
        pf[j] = abase[(size_t)(t0n + r) * NHID + n];
      }
    }
    // ---- FIR on tile t0 from ring ----
    {
      const int n = tid & 31, tq = tid >> 5;
      const int tbase = t0 + tq * 4 - 76;
      int m0 = tbase % RING; if (m0 < 0) m0 += RING;
      int len1 = RING - m0; if (len1 > 80) len1 = 80;
      double tap0 = 0.0, tap1 = 0.0, tap2 = 0.0, tap3 = 0.0;
      double c0 = 0.0, c1 = 0.0, c2 = 0.0, c3 = 0.0;
      int s = 0;
#pragma unroll 4
      for (; s < len1; ++s) {
        const double v = S[(m0 + s) * 32 + n];
        tap3 = tap2; tap2 = tap1; tap1 = tap0;
        tap0 = (s <= 76) ? srm[76 - s] : 0.0;
        c0 += tap0 * v; c1 += tap1 * v; c2 += tap2 * v; c3 += tap3 * v;
      }
#pragma unroll 4
      for (; s < 80; ++s) {
        const double v = S[(s - len1) * 32 + n];
        tap3 = tap2; tap2 = tap1; tap1 = tap0;
        tap0 = (s <= 76) ? srm[76 - s] : 0.0;
        c0 += tap0 * v; c1 += tap1 * v; c2 += tap2 * v; c3 += tap3 * v;
      }
      const int tl = tq * 4;
      if (tl + 0 < tv) Y[(tl + 0) * 32 + n] = c0;
      if (tl + 1 < tv) Y[(tl + 1) * 32 + n] = c1;
      if (tl + 2 < tv) Y[(tl + 2) * 32 + n] = c2;
      if (tl + 3 < tv) Y[(tl + 3) * 32 + n] = c3;
    }
    __syncthreads();
    // ---- refractory scan (lanes 0..31 of wave 0) ----
    if (tid < 32) {
      for (int g = 0; g < tv; ++g) {
        double u = Y[g * 32 + tid];
#pragma unroll
        for (int j = 10; j >= 1; --j)
          u += refk[j] * (double)((smask >> (j - 1)) & 1u);
        const bool sp = (u >= 10.0);
        smask = (smask << 1) | (sp ? 1u : 0u);
        const unsigned long long bm = __ballot(sp);
        if (tid == 0) sbase[(size_t)(t0 + g) * 32] = (uint32_t)bm;
      }
    }
    // ---- write prefetched tile into freed ring slots ----
#pragma unroll
    for (int j = 0; j < 4; ++j) {
      const int id = tid + j * 256;
      if (id < tvn * 32) {
        const int r = id >> 5, n = id & 31;
        S[((t0n + r) % RING) * 32 + n] = pf[j];
      }
    }
    __syncthreads();
  }
}

// ---------------------------------------------------------------------------
// K3: dense2 sparse gather from s1 u32 masks, W2 fp32 in LDS, f64 acc.
__global__ __launch_bounds__(256)
void k_dense2(const uint32_t* __restrict__ s1w,
              const float* __restrict__ W2, double* __restrict__ a2) {
  __shared__ float w2t[NHID * NOUT];  // 40 KB, [i][o]
  for (int k = threadIdx.x; k < NHID * NOUT; k += 256) {
    const int o = k >> 10, i = k & 1023;
    w2t[i * NOUT + o] = W2[k];
  }
  __syncthreads();
  const int col = blockIdx.x * 256 + threadIdx.x;  // 0..31999
  double acc[NOUT];
#pragma unroll
  for (int o = 0; o < NOUT; ++o) acc[o] = 0.0;
  const uint32_t* w = s1w + (size_t)col * 32;
  for (int wi = 0; wi < 32; ++wi) {
    uint32_t m = w[wi];
    const int ibase = wi * 32;
    while (m) {
      const int j = __ffs(m) - 1;
      m &= m - 1;
      const float* row = &w2t[(ibase + j) * NOUT];
#pragma unroll
      for (int o = 0; o < NOUT; ++o) acc[o] += (double)row[o];
    }
  }
  double* outp = a2 + (size_t)col * NOUT;
#pragma unroll
  for (int o = 0; o < NOUT; ++o) outp[o] = acc[o];
}

// ---------------------------------------------------------------------------
// K4: FUSED psp2 + spike2, one block per batch; whole [500][10] in LDS.
__global__ __launch_bounds__(256)
void k_l2(const double* __restrict__ a2, float* __restrict__ out) {
  __shared__ double S[T_SIM * NOUT];
  __shared__ double Y[T_SIM * NOUT];
  __shared__ double srm[KSRM];
  const int b = blockIdx.x, tid = threadIdx.x;
  if (tid < KSRM) srm[tid] = srm_tap(tid);
  for (int i = tid; i < T_SIM * NOUT; i += 256)
    S[i] = a2[(size_t)b * T_SIM * NOUT + i];
  __syncthreads();
  for (int i = tid; i < T_SIM * NOUT; i += 256) {
    const int t = i / 10, o = i - t * 10;
    const int kmax = (t < KSRM - 1) ? t : (KSRM - 1);
    double acc = 0.0;
    for (int k = 0; k <= kmax; ++k)
      acc += srm[k] * S[(t - k) * 10 + o];
    Y[i] = acc;
  }
  __syncthreads();
  if (tid < NOUT) {
    double refk[11];
#pragma unroll
    for (int j = 1; j <= 10; ++j) refk[j] = ref_tap(j);
    uint32_t smask = 0;
    float* op = out + ((size_t)b * NOUT + tid) * T_SIM;
    for (int t = 0; t < T_SIM; ++t) {
      double u = Y[t * 10 + tid];
#pragma unroll
      for (int j = 10; j >= 1; --j)
        u += refk[j] * (double)((smask >> (j - 1)) & 1u);
      const bool sp = (u >= 10.0);
      smask = (smask << 1) | (sp ? 1u : 0u);
      op[t] = sp ? 1.0f : 0.0f;
    }
  }
}

// ---------------------------------------------------------------------------
extern "C" void kernel_launch(void* const* d_in, const int* in_sizes, int n_in,
                              void* d_out, int out_size, void* d_ws, size_t ws_size,
                              hipStream_t stream) {
  const float* x  = (const float*)d_in[0];   // [64][1024][500]
  const float* W1 = (const float*)d_in[1];   // [1024][1024]
  const float* W2 = (const float*)d_in[2];   // [10][1024]
  float* out = (float*)d_out;                // [64][10][500]

  char* ws = (char*)d_ws;
  unsigned long long* bits1 = (unsigned long long*)(ws);   // 4,096,000
  float*  W1T = (float*) (ws + 4096000);                   // 4,194,304
  double* a1c = (double*)(ws + 8290304);                   // 131,072,000 (CHUNK=32)
  uint32_t* s1w = (uint32_t*)(ws + 139362304);             // 4,096,000
  double* a2  = (double*)(ws + 143458304);                 // 2,560,000
  // total ws use: 146,018,304 B

  hipLaunchKernelGGL(k_pack, dim3(NB, 16, 5), dim3(64), 0, stream, x, bits1);
  hipLaunchKernelGGL(k_transpose, dim3(16, 16), dim3(256), 0, stream, W1, W1T);

  for (int bc = 0; bc < NB; bc += CHUNK) {
    hipLaunchKernelGGL(k_dense1, dim3(CHUNK * T_SIM), dim3(256), 0, stream,
                       (const uint32_t*)bits1, W1T, a1c, bc * T_SIM);
    hipLaunchKernelGGL(k_ps1, dim3(32, CHUNK), dim3(256), 0, stream,
                       a1c, s1w, bc);
  }

  hipLaunchKernelGGL(k_dense2, dim3(125), dim3(256), 0, stream, s1w, W2, a2);
  hipLaunchKernelGGL(k_l2, dim3(NB), dim3(256), 0, stream, a2, out);
}